// Round 10
// baseline (470.926 us; speedup 1.0000x reference)
//
#include <hip/hip_runtime.h>

#define NN1 32768
#define NE  262144
#define FDIM 256
#define NHEADS 4
#define IN_DIM 128
#define NB 32
#define KK1 512
#define NN2 16384   // NB*KK1
#define KK2 256
#define NN3 8192    // NB*KK2
#define OUT_DIM 256
#define BN_EPS 1e-5f
#define NEG_SLOPE 0.2f

typedef _Float16 half8 __attribute__((ext_vector_type(8)));
typedef _Float16 half4v __attribute__((ext_vector_type(4)));
typedef float floatx4 __attribute__((ext_vector_type(4)));

__device__ __forceinline__ float lrelu(float x) { return x >= 0.f ? x : NEG_SLOPE * x; }
__device__ __forceinline__ float gelu(float v) {
  return 0.5f * v * (1.0f + erff(v * 0.7071067811865476f));
}
// XCD swizzle: total blocks = 32*U (U units/graph). blk%8 -> XCD; XCD x owns graphs {x,x+8,x+16,x+24}.
#define SWIZ(U) int g, u; { int _x = blockIdx.x & 7, _i = blockIdx.x >> 3; g = _x + 8 * (_i / (U)); u = _i % (U); }

// ---------- fused 2-level scan body of (deg+1): block b redundantly sums deg[0..b*1024)
template <int N>
__device__ void scan_body(const int* __restrict__ deg, int* __restrict__ rowst,
                          int* __restrict__ cursor, int b, int tid) {
  __shared__ int redS[4];
  __shared__ int swsumS[4];
  int lane = tid & 63, wv = tid >> 6;
  int part = 0;
  for (int idx = tid * 4; idx < b * 1024; idx += 1024) {
    int4 v = *(const int4*)&deg[idx];
    part += v.x + v.y + v.z + v.w;
  }
#pragma unroll
  for (int off = 32; off > 0; off >>= 1) part += __shfl_xor(part, off);
  if (lane == 0) redS[wv] = part;
  __syncthreads();
  int goff = redS[0] + redS[1] + redS[2] + redS[3] + b * 1024;  // + prior self loops
  int base = b * 1024 + tid * 4;
  int4 dv = *(const int4*)&deg[base];
  int v0 = dv.x + 1, v1 = dv.y + 1, v2 = dv.z + 1, v3 = dv.w + 1;
  int local = v0 + v1 + v2 + v3;
  int xx = local;
#pragma unroll
  for (int off = 1; off < 64; off <<= 1) {
    int t = __shfl_up(xx, off);
    if (lane >= off) xx += t;
  }
  if (lane == 63) swsumS[wv] = xx;
  __syncthreads();
  int woff = 0;
  for (int i = 0; i < wv; ++i) woff += swsumS[i];
  int ex = goff + woff + xx - local;
  int4 o;
  o.x = ex; o.y = ex + v0; o.z = ex + v0 + v1; o.w = ex + v0 + v1 + v2;
  *(int4*)&rowst[base] = o;
  *(int4*)&cursor[base] = o;
  if (b == (N / 1024) - 1 && tid == 0)
    rowst[N] = goff + swsumS[0] + swsumS[1] + swsumS[2] + swsumS[3];
}

template <int N>
__global__ void scanF_k(const int* __restrict__ deg, int* __restrict__ rowst,
                        int* __restrict__ cursor) {
  scan_body<N>(deg, rowst, cursor, blockIdx.x, threadIdx.x);
}

// ---------- init: x->fp16, W1^T, W2^T, zero deg1/deg2/inv1/bnstats ----------
__global__ void init_k(const float4* __restrict__ x, half4v* __restrict__ ah,
                       const float* __restrict__ W1, _Float16* __restrict__ bt1,
                       const float* __restrict__ W2, _Float16* __restrict__ bt2,
                       int* __restrict__ deg1, int* __restrict__ deg2,
                       int* __restrict__ inv1, float* __restrict__ bnst) {
  int blk = blockIdx.x, tid = threadIdx.x;
  if (blk < 4096) {
    int i = blk * 256 + tid;
    float4 v = x[i];
    half4v h;
    h[0] = (_Float16)v.x; h[1] = (_Float16)v.y; h[2] = (_Float16)v.z; h[3] = (_Float16)v.w;
    ah[i] = h;
  } else if (blk < 4224) {                // W1[128][256] -> bt1[256][128]
    int idx = (blk - 4096) * 256 + tid;
    int n = idx >> 7, k = idx & 127;
    bt1[idx] = (_Float16)W1[k * FDIM + n];
  } else if (blk < 4480) {                // W2[256][256] -> bt2[256][256]
    int idx = (blk - 4224) * 256 + tid;
    int n = idx >> 8, k = idx & 255;
    bt2[idx] = (_Float16)W2[k * FDIM + n];
  } else {
    int i = (blk - 4480) * 256 + tid;
    deg1[i] = 0;
    inv1[i] = -1;
    if (i < NN2) deg2[i] = 0;
    if (i < 1024) bnst[i] = 0.f;
  }
}

// ---------------- MFMA fp16 GEMM + fused attn-coef epilogue + ride-along (deg OR scan)
template <int K, int MBLK, int DEGU, int SCAN_N>
__global__ void gemm_attn_k(const _Float16* __restrict__ A, const _Float16* __restrict__ BT,
                            _Float16* __restrict__ C, const float* __restrict__ a_s,
                            const float* __restrict__ a_d, float* __restrict__ asn,
                            float* __restrict__ adn, const int* __restrict__ dstE,
                            int* __restrict__ deg, const int* __restrict__ sdeg,
                            int* __restrict__ srow, int* __restrict__ scur) {
  if ((int)blockIdx.y >= MBLK) {
    int unit = blockIdx.x + 2 * (blockIdx.y - MBLK);
    if constexpr (DEGU > 0) {
      int e = unit * 256 + threadIdx.x;
      if (e < NE) {
        int dd = dstE[e];
        if (dd >= 0) atomicAdd(&deg[dd], 1);
      }
    } else if constexpr (SCAN_N > 0) {
      scan_body<SCAN_N>(sdeg, srow, scur, unit, threadIdx.x);
    }
    return;
  }
  __shared__ _Float16 As[64 * 40];
  __shared__ _Float16 Bs[128 * 40];
  int tid = threadIdx.x;
  int lane = tid & 63, w = tid >> 6;
  int bm = blockIdx.y * 64, bn = blockIdx.x * 128;
  int wm = (w & 1) * 32, wn = (w >> 1) * 64;
  floatx4 acc[2][4] = {};
  int ar = tid >> 2, ac = (tid & 3) * 8;
  int br = tid >> 1, bc = (tid & 1) * 16;
  int fm = lane & 15, fq = (lane >> 4) * 8;
  for (int k0 = 0; k0 < K; k0 += 32) {
    __syncthreads();
    *(half8*)&As[ar * 40 + ac] = *(const half8*)&A[(size_t)(bm + ar) * K + k0 + ac];
    *(half8*)&Bs[br * 40 + bc] = *(const half8*)&BT[(size_t)(bn + br) * K + k0 + bc];
    *(half8*)&Bs[br * 40 + bc + 8] = *(const half8*)&BT[(size_t)(bn + br) * K + k0 + bc + 8];
    __syncthreads();
    half8 af[2], bf[4];
#pragma unroll
    for (int mt = 0; mt < 2; ++mt)
      af[mt] = *(const half8*)&As[(wm + mt * 16 + fm) * 40 + fq];
#pragma unroll
    for (int nt = 0; nt < 4; ++nt)
      bf[nt] = *(const half8*)&Bs[(wn + nt * 16 + fm) * 40 + fq];
#pragma unroll
    for (int mt = 0; mt < 2; ++mt)
#pragma unroll
      for (int nt = 0; nt < 4; ++nt)
        acc[mt][nt] = __builtin_amdgcn_mfma_f32_16x16x32_f16(af[mt], bf[nt], acc[mt][nt], 0, 0, 0);
  }
  int row0 = bm + wm + (lane >> 4) * 4;
  int col0 = bn + wn + (lane & 15);
#pragma unroll
  for (int mt = 0; mt < 2; ++mt)
#pragma unroll
    for (int nt = 0; nt < 4; ++nt) {
      _Float16* cp = C + (size_t)(row0 + mt * 16) * FDIM + col0 + nt * 16;
#pragma unroll
      for (int i = 0; i < 4; ++i) cp[(size_t)i * FDIM] = (_Float16)acc[mt][nt][i];
    }
  // attn-coef epilogue (wave = one head)
  int head = (bn + wn) >> 6;
  float ps[2][4] = {}, pd[2][4] = {};
#pragma unroll
  for (int nt = 0; nt < 4; ++nt) {
    int c = bn + wn + (lane & 15) + nt * 16;
    float asv = a_s[c], adv = a_d[c];
#pragma unroll
    for (int mt = 0; mt < 2; ++mt)
#pragma unroll
      for (int i = 0; i < 4; ++i) {
        ps[mt][i] = fmaf(acc[mt][nt][i], asv, ps[mt][i]);
        pd[mt][i] = fmaf(acc[mt][nt][i], adv, pd[mt][i]);
      }
  }
#pragma unroll
  for (int off = 8; off >= 1; off >>= 1)
#pragma unroll
    for (int mt = 0; mt < 2; ++mt)
#pragma unroll
      for (int i = 0; i < 4; ++i) {
        ps[mt][i] += __shfl_xor(ps[mt][i], off);
        pd[mt][i] += __shfl_xor(pd[mt][i], off);
      }
  if ((lane & 15) == 0) {
#pragma unroll
    for (int mt = 0; mt < 2; ++mt)
#pragma unroll
      for (int i = 0; i < 4; ++i) {
        int r = row0 + mt * 16 + i;
        asn[r * 4 + head] = ps[mt][i];
        adn[r * 4 + head] = pd[mt][i];
      }
  }
}

// ---------------- CSR fill (XCD-swizzled): EU edge-units + SU selfloop-units per graph
template <int NPG, int EU, int SU>
__global__ void csr_fill_k(const int* __restrict__ src, const int* __restrict__ dst,
                           int* __restrict__ cursor, const float4* __restrict__ asn4,
                           const float4* __restrict__ adn4, int* __restrict__ csrc,
                           float4* __restrict__ pexp) {
  int tid = threadIdx.x;
  int s, d;
  if ((int)blockIdx.x < 32 * EU) {
    SWIZ(EU);
    int e = g * 8192 + u * 256 + tid;
    d = dst[e];
    if (d < 0) return;
    s = src[e];
  } else {
    int bb = blockIdx.x - 32 * EU;
    int _x = bb & 7, _i = bb >> 3;
    int g = _x + 8 * (_i / SU), u = _i % SU;
    s = d = g * NPG + u * 256 + tid;
  }
  int pos = atomicAdd(&cursor[d], 1);
  csrc[pos] = s;
  float4 A4 = asn4[s], B4 = adn4[d];
  float4 p;
  p.x = expf(lrelu(A4.x + B4.x));
  p.y = expf(lrelu(A4.y + B4.y));
  p.z = expf(lrelu(A4.z + B4.z));
  p.w = expf(lrelu(A4.w + B4.w));
  pexp[pos] = p;
}

// ---------------- GAT aggregate + GELU -> o16 (XCD-swizzled; 4-edge ILP)
template <int NPG>
__global__ void gat_agg_k(const _Float16* __restrict__ h, const int* __restrict__ rowstart,
                          const int* __restrict__ csrc, const float* __restrict__ pexpf,
                          const float* __restrict__ bias, _Float16* __restrict__ out) {
  SWIZ(NPG / 4);
  int tid = threadIdx.x, lane = tid & 63;
  int hw = lane >> 5, l = lane & 31;
  int d = g * NPG + u * 4 + (tid >> 6);
  int beg = rowstart[d], end = rowstart[d + 1];
  int c0 = l * 8, head = l >> 3;
  float acc[8] = {};
  float de = 0.f;
  for (int i = beg; i < end; i += 4) {
    int e0 = i + hw, e1 = i + 2 + hw;
    bool va = e0 < end, vb = e1 < end;
    int s0 = va ? csrc[e0] : csrc[beg];
    int s1 = vb ? csrc[e1] : csrc[beg];
    float p0 = va ? pexpf[e0 * 4 + head] : 0.f;
    float p1 = vb ? pexpf[e1 * 4 + head] : 0.f;
    float4 hv0 = *(const float4*)(h + (size_t)s0 * FDIM + c0);
    float4 hv1 = *(const float4*)(h + (size_t)s1 * FDIM + c0);
    const _Float16* h0 = (const _Float16*)&hv0;
    const _Float16* h1 = (const _Float16*)&hv1;
    de += p0 + p1;
#pragma unroll
    for (int j = 0; j < 8; ++j)
      acc[j] = fmaf(p1, (float)h1[j], fmaf(p0, (float)h0[j], acc[j]));
  }
#pragma unroll
  for (int j = 0; j < 8; ++j) acc[j] += __shfl_xor(acc[j], 32);
  de += __shfl_xor(de, 32);
  if (hw == 0) {
    float inv = 1.f / de;
    _Float16 o[8];
#pragma unroll
    for (int j = 0; j < 8; ++j) o[j] = (_Float16)gelu(acc[j] * inv + bias[c0 + j]);
    *(float4*)(out + (size_t)d * FDIM + c0) = *(const float4*)o;
  }
}

// ---------------- BN stats (XCD-swizzled, 8 units/graph)
template <int NPG>
__global__ void stats_k(const _Float16* __restrict__ x, float* __restrict__ sum,
                        float* __restrict__ sumsq) {
  SWIZ(8);
  constexpr int RPB = NPG / 8;
  int f = threadIdx.x;
  int r0 = g * NPG + u * RPB;
  float s = 0.f, sq = 0.f;
  for (int r = r0; r < r0 + RPB; ++r) {
    float gg = (float)x[(size_t)r * FDIM + f];
    s += gg;
    sq += gg * gg;
  }
  atomicAdd(&sum[f], s);
  atomicAdd(&sumsq[f], sq);
}

// ---------------- topk with fused score (deferred-BN affine fold computed in-block)
template <int NPG, int KEEP, int NTOT>
__global__ void topk_k(const _Float16* __restrict__ x, const float* __restrict__ bnsum,
                       const float* __restrict__ bnsq, const float* __restrict__ g_,
                       const float* __restrict__ be, const float* __restrict__ w,
                       float* __restrict__ vals, int* __restrict__ gidx,
                       int* __restrict__ inv) {
  constexpr int TPG = NPG / 256;
  SWIZ(TPG);
  __shared__ __align__(16) float sv[NPG];
  __shared__ float scw[FDIM];
  __shared__ float redf[8];
  constexpr float INV_N = 1.0f / NTOT;
  int tid = threadIdx.x, lane = tid & 63, wvz = tid >> 6;
  {
    int c = tid;
    float mean = bnsum[c] * INV_N;
    float var = bnsq[c] * INV_N - mean * mean;
    float sc = g_[c] / sqrtf(var + BN_EPS);
    float sh = be[c] - mean * sc;
    float wvv = w[c];
    scw[c] = sc * wvv;
    float shw = sh * wvv, nw = wvv * wvv;
#pragma unroll
    for (int off = 32; off > 0; off >>= 1) {
      shw += __shfl_xor(shw, off);
      nw += __shfl_xor(nw, off);
    }
    if (lane == 0) { redf[wvz] = shw; redf[4 + wvz] = nw; }
  }
  __syncthreads();
  float SHW = redf[0] + redf[1] + redf[2] + redf[3];
  float SQN = sqrtf(redf[4] + redf[5] + redf[6] + redf[7]);
  int c0 = lane * 4;
  float w0 = scw[c0], w1 = scw[c0 + 1], w2 = scw[c0 + 2], w3 = scw[c0 + 3];
  for (int n = wvz; n < NPG; n += 4) {
    float2 raw = *(const float2*)(x + (size_t)(g * NPG + n) * FDIM + c0);
    const _Float16* hh = (const _Float16*)&raw;
    float p = fmaf((float)hh[0], w0, 0.f);
    p = fmaf((float)hh[1], w1, p);
    p = fmaf((float)hh[2], w2, p);
    p = fmaf((float)hh[3], w3, p);
#pragma unroll
    for (int off = 32; off > 0; off >>= 1) p += __shfl_xor(p, off);
    if (lane == 0) sv[n] = (p + SHW) / SQN;
  }
  __syncthreads();
  int cand = u * 256 + tid;
  float v = sv[cand];
  int rank = 0;
  const float4* sv4 = (const float4*)sv;
  for (int j4 = 0; j4 < NPG / 4; ++j4) {
    float4 qd = sv4[j4];
    int jb = j4 * 4;
    rank += (qd.x > v) || (qd.x == v && (jb + 0) < cand);
    rank += (qd.y > v) || (qd.y == v && (jb + 1) < cand);
    rank += (qd.z > v) || (qd.z == v && (jb + 2) < cand);
    rank += (qd.w > v) || (qd.w == v && (jb + 3) < cand);
  }
  if (rank < KEEP) {
    int r = g * KEEP + rank;
    vals[r] = v;
    int gg2 = g * NPG + cand;
    gidx[r] = gg2;
    if (inv) inv[gg2] = r;
  }
}

// ---------------- pool (BN+tanh fused gather + readout partials), L1 adds remap+deg2 ride
template <int NPG, int KEEP, bool EMIT, bool REMAP, int NTOT>
__global__ void pool_k(const _Float16* __restrict__ x, const int* __restrict__ gidx,
                       const float* __restrict__ vals, const float* __restrict__ bnsum,
                       const float* __restrict__ bnsq, const float* __restrict__ g_,
                       const float* __restrict__ be, _Float16* __restrict__ ah,
                       float* __restrict__ pmax, float* __restrict__ psum,
                       const int* __restrict__ src0, const int* __restrict__ dst0,
                       const int* __restrict__ inv, int* __restrict__ ns,
                       int* __restrict__ nd, int* __restrict__ deg2) {
  constexpr int PU = KEEP / 16;
  constexpr float INV_N = 1.0f / NTOT;
  int f = threadIdx.x;
  if ((int)blockIdx.x < 32 * PU) {
    SWIZ(PU);
    float mean = bnsum[f] * INV_N;
    float var = bnsq[f] * INV_N - mean * mean;
    float sc = g_[f] / sqrtf(var + BN_EPS);
    float sh = be[f] - mean * sc;
    float mx = -3.0e38f, sm = 0.f;
    int r0 = g * KEEP + u * 16;
#pragma unroll 4
    for (int j = 0; j < 16; ++j) {
      int r = r0 + j;
      float t = tanhf(vals[r]);
      float rawv = (float)x[(size_t)gidx[r] * FDIM + f];
      float vv = fmaf(rawv, sc, sh) * t;
      if (EMIT) ah[(size_t)r * FDIM + f] = (_Float16)vv;
      mx = fmaxf(mx, vv);
      sm += vv;
    }
    int blk = g * PU + u;
    pmax[(size_t)blk * FDIM + f] = mx;
    psum[(size_t)blk * FDIM + f] = sm;
  } else if (REMAP) {
    int bb = blockIdx.x - 32 * PU;
    int _x = bb & 7, _i = bb >> 3;
    int g = _x + 8 * (_i / 32), u = _i % 32;
    int e = g * 8192 + u * 256 + f;
    int aa = inv[src0[e]], b2 = inv[dst0[e]];
    bool ok = (aa >= 0) && (b2 >= 0);
    ns[e] = ok ? aa : -1;
    nd[e] = ok ? b2 : -1;
    if (ok) atomicAdd(&deg2[b2], 1);
  }
}

// ---------------- readout-final (both layers) + output linear
__global__ void final_k(const float* __restrict__ pmax1, const float* __restrict__ psum1,
                        const float* __restrict__ pmax2, const float* __restrict__ psum2,
                        const float* __restrict__ Wl, const float* __restrict__ bl,
                        float* __restrict__ out) {
  __shared__ float xs[2 * FDIM];
  int b = blockIdx.x, f = threadIdx.x;
  float mx1 = -3.0e38f, s1 = 0.f, mx2 = -3.0e38f, s2 = 0.f;
  for (int s = 0; s < KK1 / 16; ++s) {
    mx1 = fmaxf(mx1, pmax1[(size_t)(b * (KK1 / 16) + s) * FDIM + f]);
    s1 += psum1[(size_t)(b * (KK1 / 16) + s) * FDIM + f];
  }
  for (int s = 0; s < KK2 / 16; ++s) {
    mx2 = fmaxf(mx2, pmax2[(size_t)(b * (KK2 / 16) + s) * FDIM + f]);
    s2 += psum2[(size_t)(b * (KK2 / 16) + s) * FDIM + f];
  }
  xs[f] = mx1 + mx2;
  xs[FDIM + f] = s1 * (1.0f / KK1) + s2 * (1.0f / KK2);
  __syncthreads();
  float acc = bl[f];
  const float* wp = Wl + (size_t)f * 512;
  for (int j = 0; j < 512; ++j) acc = fmaf(xs[j], wp[j], acc);
  out[b * OUT_DIM + f] = acc;
}

extern "C" void kernel_launch(void* const* d_in, const int* in_sizes, int n_in,
                              void* d_out, int out_size, void* d_ws, size_t ws_size,
                              hipStream_t stream) {
  (void)in_sizes; (void)n_in; (void)out_size; (void)ws_size;
  const float* x   = (const float*)d_in[0];
  const int* eidx  = (const int*)d_in[1];
  const int* src   = eidx;
  const int* dst   = eidx + NE;
  const float* W1  = (const float*)d_in[3];
  const float* as1 = (const float*)d_in[4];
  const float* ad1 = (const float*)d_in[5];
  const float* b1  = (const float*)d_in[6];
  const float* g1  = (const float*)d_in[7];
  const float* be1 = (const float*)d_in[8];
  const float* pw1 = (const float*)d_in[9];
  const float* W2  = (const float*)d_in[10];
  const float* as2 = (const float*)d_in[11];
  const float* ad2 = (const float*)d_in[12];
  const float* b2  = (const float*)d_in[13];
  const float* g2  = (const float*)d_in[14];
  const float* be2 = (const float*)d_in[15];
  const float* pw2 = (const float*)d_in[16];
  const float* Wl  = (const float*)d_in[17];
  const float* bl  = (const float*)d_in[18];
  float* out = (float*)d_out;

  char* wsp = (char*)d_ws;
  size_t off = 0;
  auto alloc = [&](size_t bytes) -> void* {
    void* p = wsp + off;
    off += (bytes + 255) & ~(size_t)255;
    return p;
  };
  _Float16* h16 = (_Float16*)alloc((size_t)NN1 * FDIM * 2);
  _Float16* o16 = (_Float16*)alloc((size_t)NN1 * FDIM * 2);
  _Float16* ah  = (_Float16*)alloc((size_t)NN1 * IN_DIM * 2);
  _Float16* bt1 = (_Float16*)alloc((size_t)FDIM * IN_DIM * 2);
  _Float16* bt2 = (_Float16*)alloc((size_t)FDIM * FDIM * 2);
  float* asn    = (float*)alloc((size_t)NN1 * NHEADS * 4);
  float* adn    = (float*)alloc((size_t)NN1 * NHEADS * 4);
  float* pexp   = (float*)alloc((size_t)(NE + NN1) * 16);
  int*   deg1   = (int*)alloc((size_t)NN1 * 4);
  int*   deg2   = (int*)alloc((size_t)NN2 * 4);
  int*   rowst  = (int*)alloc((size_t)(NN1 + 1) * 4);
  int*   cursor = (int*)alloc((size_t)NN1 * 4);
  int*   csrc   = (int*)alloc((size_t)(NE + NN1) * 4);
  int*   ns     = (int*)alloc((size_t)NE * 4);
  int*   nd     = (int*)alloc((size_t)NE * 4);
  int*   inv1   = (int*)alloc((size_t)NN1 * 4);
  float* vals   = (float*)alloc((size_t)NN2 * 4);
  int*   gidx   = (int*)alloc((size_t)NN2 * 4);
  float* bnst   = (float*)alloc(1024 * 4);
  float* pmax1  = (float*)alloc((size_t)(NN2 / 16) * FDIM * 4);
  float* psum1  = (float*)alloc((size_t)(NN2 / 16) * FDIM * 4);
  float* pmax2  = (float*)alloc((size_t)(NN3 / 16) * FDIM * 4);
  float* psum2  = (float*)alloc((size_t)(NN3 / 16) * FDIM * 4);

  // ---------- layer 1 ----------
  init_k<<<4608, 256, 0, stream>>>((const float4*)x, (half4v*)ah, W1, bt1, W2, bt2,
                                   deg1, deg2, inv1, bnst);
  gemm_attn_k<IN_DIM, 512, 1024, 0><<<dim3(2, 1024), 256, 0, stream>>>(
      ah, bt1, h16, as1, ad1, asn, adn, dst, deg1, nullptr, nullptr, nullptr);
  scanF_k<NN1><<<NN1 / 1024, 256, 0, stream>>>(deg1, rowst, cursor);
  csr_fill_k<1024, 32, 4><<<1024 + 128, 256, 0, stream>>>(
      src, dst, cursor, (const float4*)asn, (const float4*)adn, csrc, (float4*)pexp);
  gat_agg_k<1024><<<NN1 / 4, 256, 0, stream>>>(h16, rowst, csrc, pexp, b1, o16);
  stats_k<1024><<<256, 256, 0, stream>>>(o16, bnst, bnst + 256);
  topk_k<1024, 512, NN1><<<NB * 4, 256, 0, stream>>>(o16, bnst, bnst + 256, g1, be1, pw1,
                                                     vals, gidx, inv1);
  pool_k<1024, 512, true, true, NN1><<<1024 + 1024, 256, 0, stream>>>(
      o16, gidx, vals, bnst, bnst + 256, g1, be1, ah, pmax1, psum1,
      src, dst, inv1, ns, nd, deg2);
  // ---------- layer 2 ----------
  gemm_attn_k<FDIM, 256, 0, NN2><<<dim3(2, 256 + 8), 256, 0, stream>>>(
      ah, bt2, h16, as2, ad2, asn, adn, nullptr, nullptr, deg2, rowst, cursor);
  csr_fill_k<512, 32, 2><<<1024 + 64, 256, 0, stream>>>(
      ns, nd, cursor, (const float4*)asn, (const float4*)adn, csrc, (float4*)pexp);
  gat_agg_k<512><<<NN2 / 4, 256, 0, stream>>>(h16, rowst, csrc, pexp, b2, o16);
  stats_k<512><<<256, 256, 0, stream>>>(o16, bnst + 512, bnst + 768);
  topk_k<512, 256, NN2><<<NB * 2, 256, 0, stream>>>(o16, bnst + 512, bnst + 768, g2, be2,
                                                    pw2, vals, gidx, nullptr);
  pool_k<512, 256, false, false, NN2><<<512, 256, 0, stream>>>(
      o16, gidx, vals, bnst + 512, bnst + 768, g2, be2, nullptr, pmax2, psum2,
      nullptr, nullptr, nullptr, nullptr, nullptr, nullptr);
  // ---------- final ----------
  final_k<<<NB, 256, 0, stream>>>(pmax1, psum1, pmax2, psum2, Wl, bl, out);
}

// Round 11
// 348.805 us; speedup vs baseline: 1.3501x; 1.3501x over previous
//
#include <hip/hip_runtime.h>

#define NN1 32768
#define NE  262144
#define FDIM 256
#define NHEADS 4
#define IN_DIM 128
#define NB 32
#define KK1 512
#define NN2 16384   // NB*KK1
#define KK2 256
#define NN3 8192    // NB*KK2
#define OUT_DIM 256
#define BN_EPS 1e-5f
#define NEG_SLOPE 0.2f

typedef _Float16 half8 __attribute__((ext_vector_type(8)));
typedef _Float16 half4v __attribute__((ext_vector_type(4)));
typedef float floatx4 __attribute__((ext_vector_type(4)));

__device__ __forceinline__ float lrelu(float x) { return x >= 0.f ? x : NEG_SLOPE * x; }
__device__ __forceinline__ float gelu(float v) {
  return 0.5f * v * (1.0f + erff(v * 0.7071067811865476f));
}
// XCD swizzle: total blocks = 32*U (U units/graph). blk%8 -> XCD; XCD x owns graphs {x,x+8,x+16,x+24}.
#define SWIZ(U) int g, u; { int _x = blockIdx.x & 7, _i = blockIdx.x >> 3; g = _x + 8 * (_i / (U)); u = _i % (U); }

// ---------- fused 2-level scan body of (deg+1): block b redundantly sums deg[0..b*1024)
template <int N>
__device__ void scan_body(const int* __restrict__ deg, int* __restrict__ rowst,
                          int* __restrict__ cursor, int b, int tid) {
  __shared__ int redS[4];
  __shared__ int swsumS[4];
  int lane = tid & 63, wv = tid >> 6;
  int part = 0;
  for (int idx = tid * 4; idx < b * 1024; idx += 1024) {
    int4 v = *(const int4*)&deg[idx];
    part += v.x + v.y + v.z + v.w;
  }
#pragma unroll
  for (int off = 32; off > 0; off >>= 1) part += __shfl_xor(part, off);
  if (lane == 0) redS[wv] = part;
  __syncthreads();
  int goff = redS[0] + redS[1] + redS[2] + redS[3] + b * 1024;  // + prior self loops
  int base = b * 1024 + tid * 4;
  int4 dv = *(const int4*)&deg[base];
  int v0 = dv.x + 1, v1 = dv.y + 1, v2 = dv.z + 1, v3 = dv.w + 1;
  int local = v0 + v1 + v2 + v3;
  int xx = local;
#pragma unroll
  for (int off = 1; off < 64; off <<= 1) {
    int t = __shfl_up(xx, off);
    if (lane >= off) xx += t;
  }
  if (lane == 63) swsumS[wv] = xx;
  __syncthreads();
  int woff = 0;
  for (int i = 0; i < wv; ++i) woff += swsumS[i];
  int ex = goff + woff + xx - local;
  int4 o;
  o.x = ex; o.y = ex + v0; o.z = ex + v0 + v1; o.w = ex + v0 + v1 + v2;
  *(int4*)&rowst[base] = o;
  *(int4*)&cursor[base] = o;
  if (b == (N / 1024) - 1 && tid == 0)
    rowst[N] = goff + swsumS[0] + swsumS[1] + swsumS[2] + swsumS[3];
}

template <int N>
__global__ void scanF_k(const int* __restrict__ deg, int* __restrict__ rowst,
                        int* __restrict__ cursor) {
  scan_body<N>(deg, rowst, cursor, blockIdx.x, threadIdx.x);
}

// ---------- init: x->fp16, W1^T, W2^T, zero deg1/deg2/inv1/bnstats ----------
__global__ void init_k(const float4* __restrict__ x, half4v* __restrict__ ah,
                       const float* __restrict__ W1, _Float16* __restrict__ bt1,
                       const float* __restrict__ W2, _Float16* __restrict__ bt2,
                       int* __restrict__ deg1, int* __restrict__ deg2,
                       int* __restrict__ inv1, float* __restrict__ bnst) {
  int blk = blockIdx.x, tid = threadIdx.x;
  if (blk < 4096) {
    int i = blk * 256 + tid;
    float4 v = x[i];
    half4v h;
    h[0] = (_Float16)v.x; h[1] = (_Float16)v.y; h[2] = (_Float16)v.z; h[3] = (_Float16)v.w;
    ah[i] = h;
  } else if (blk < 4224) {                // W1[128][256] -> bt1[256][128]
    int idx = (blk - 4096) * 256 + tid;
    int n = idx >> 7, k = idx & 127;
    bt1[idx] = (_Float16)W1[k * FDIM + n];
  } else if (blk < 4480) {                // W2[256][256] -> bt2[256][256]
    int idx = (blk - 4224) * 256 + tid;
    int n = idx >> 8, k = idx & 255;
    bt2[idx] = (_Float16)W2[k * FDIM + n];
  } else {
    int i = (blk - 4480) * 256 + tid;
    deg1[i] = 0;
    inv1[i] = -1;
    if (i < NN2) deg2[i] = 0;
    if (i < 1024) bnst[i] = 0.f;
  }
}

// ---------------- MFMA fp16 GEMM + fused attn-coef epilogue + ride-along (deg OR scan)
template <int K, int MBLK, int DEGU, int SCAN_N>
__global__ void gemm_attn_k(const _Float16* __restrict__ A, const _Float16* __restrict__ BT,
                            _Float16* __restrict__ C, const float* __restrict__ a_s,
                            const float* __restrict__ a_d, float* __restrict__ asn,
                            float* __restrict__ adn, const int* __restrict__ dstE,
                            int* __restrict__ deg, const int* __restrict__ sdeg,
                            int* __restrict__ srow, int* __restrict__ scur) {
  if ((int)blockIdx.y >= MBLK) {
    int unit = blockIdx.x + 2 * (blockIdx.y - MBLK);
    if constexpr (DEGU > 0) {
      int e = unit * 256 + threadIdx.x;
      if (e < NE) {
        int dd = dstE[e];
        if (dd >= 0) atomicAdd(&deg[dd], 1);
      }
    } else if constexpr (SCAN_N > 0) {
      scan_body<SCAN_N>(sdeg, srow, scur, unit, threadIdx.x);
    }
    return;
  }
  __shared__ _Float16 As[64 * 40];
  __shared__ _Float16 Bs[128 * 40];
  int tid = threadIdx.x;
  int lane = tid & 63, w = tid >> 6;
  int bm = blockIdx.y * 64, bn = blockIdx.x * 128;
  int wm = (w & 1) * 32, wn = (w >> 1) * 64;
  floatx4 acc[2][4] = {};
  int ar = tid >> 2, ac = (tid & 3) * 8;
  int br = tid >> 1, bc = (tid & 1) * 16;
  int fm = lane & 15, fq = (lane >> 4) * 8;
  for (int k0 = 0; k0 < K; k0 += 32) {
    __syncthreads();
    *(half8*)&As[ar * 40 + ac] = *(const half8*)&A[(size_t)(bm + ar) * K + k0 + ac];
    *(half8*)&Bs[br * 40 + bc] = *(const half8*)&BT[(size_t)(bn + br) * K + k0 + bc];
    *(half8*)&Bs[br * 40 + bc + 8] = *(const half8*)&BT[(size_t)(bn + br) * K + k0 + bc + 8];
    __syncthreads();
    half8 af[2], bf[4];
#pragma unroll
    for (int mt = 0; mt < 2; ++mt)
      af[mt] = *(const half8*)&As[(wm + mt * 16 + fm) * 40 + fq];
#pragma unroll
    for (int nt = 0; nt < 4; ++nt)
      bf[nt] = *(const half8*)&Bs[(wn + nt * 16 + fm) * 40 + fq];
#pragma unroll
    for (int mt = 0; mt < 2; ++mt)
#pragma unroll
      for (int nt = 0; nt < 4; ++nt)
        acc[mt][nt] = __builtin_amdgcn_mfma_f32_16x16x32_f16(af[mt], bf[nt], acc[mt][nt], 0, 0, 0);
  }
  int row0 = bm + wm + (lane >> 4) * 4;
  int col0 = bn + wn + (lane & 15);
#pragma unroll
  for (int mt = 0; mt < 2; ++mt)
#pragma unroll
    for (int nt = 0; nt < 4; ++nt) {
      _Float16* cp = C + (size_t)(row0 + mt * 16) * FDIM + col0 + nt * 16;
#pragma unroll
      for (int i = 0; i < 4; ++i) cp[(size_t)i * FDIM] = (_Float16)acc[mt][nt][i];
    }
  // attn-coef epilogue (wave = one head)
  int head = (bn + wn) >> 6;
  float ps[2][4] = {}, pd[2][4] = {};
#pragma unroll
  for (int nt = 0; nt < 4; ++nt) {
    int c = bn + wn + (lane & 15) + nt * 16;
    float asv = a_s[c], adv = a_d[c];
#pragma unroll
    for (int mt = 0; mt < 2; ++mt)
#pragma unroll
      for (int i = 0; i < 4; ++i) {
        ps[mt][i] = fmaf(acc[mt][nt][i], asv, ps[mt][i]);
        pd[mt][i] = fmaf(acc[mt][nt][i], adv, pd[mt][i]);
      }
  }
#pragma unroll
  for (int off = 8; off >= 1; off >>= 1)
#pragma unroll
    for (int mt = 0; mt < 2; ++mt)
#pragma unroll
      for (int i = 0; i < 4; ++i) {
        ps[mt][i] += __shfl_xor(ps[mt][i], off);
        pd[mt][i] += __shfl_xor(pd[mt][i], off);
      }
  if ((lane & 15) == 0) {
#pragma unroll
    for (int mt = 0; mt < 2; ++mt)
#pragma unroll
      for (int i = 0; i < 4; ++i) {
        int r = row0 + mt * 16 + i;
        asn[r * 4 + head] = ps[mt][i];
        adn[r * 4 + head] = pd[mt][i];
      }
  }
}

// ---------------- CSR fill (XCD-swizzled): EU edge-units + SU selfloop-units per graph
template <int NPG, int EU, int SU>
__global__ void csr_fill_k(const int* __restrict__ src, const int* __restrict__ dst,
                           int* __restrict__ cursor, const float4* __restrict__ asn4,
                           const float4* __restrict__ adn4, int* __restrict__ csrc,
                           float4* __restrict__ pexp) {
  int tid = threadIdx.x;
  int s, d;
  if ((int)blockIdx.x < 32 * EU) {
    SWIZ(EU);
    int e = g * 8192 + u * 256 + tid;
    d = dst[e];
    if (d < 0) return;
    s = src[e];
  } else {
    int bb = blockIdx.x - 32 * EU;
    int _x = bb & 7, _i = bb >> 3;
    int g = _x + 8 * (_i / SU), u = _i % SU;
    s = d = g * NPG + u * 256 + tid;
  }
  int pos = atomicAdd(&cursor[d], 1);
  csrc[pos] = s;
  float4 A4 = asn4[s], B4 = adn4[d];
  float4 p;
  p.x = expf(lrelu(A4.x + B4.x));
  p.y = expf(lrelu(A4.y + B4.y));
  p.z = expf(lrelu(A4.z + B4.z));
  p.w = expf(lrelu(A4.w + B4.w));
  pexp[pos] = p;
}

// ---------------- GAT aggregate + GELU -> o16 (XCD-swizzled; 4-edge ILP)
template <int NPG>
__global__ void gat_agg_k(const _Float16* __restrict__ h, const int* __restrict__ rowstart,
                          const int* __restrict__ csrc, const float* __restrict__ pexpf,
                          const float* __restrict__ bias, _Float16* __restrict__ out) {
  SWIZ(NPG / 4);
  int tid = threadIdx.x, lane = tid & 63;
  int hw = lane >> 5, l = lane & 31;
  int d = g * NPG + u * 4 + (tid >> 6);
  int beg = rowstart[d], end = rowstart[d + 1];
  int c0 = l * 8, head = l >> 3;
  float acc[8] = {};
  float de = 0.f;
  for (int i = beg; i < end; i += 4) {
    int e0 = i + hw, e1 = i + 2 + hw;
    bool va = e0 < end, vb = e1 < end;
    int s0 = va ? csrc[e0] : csrc[beg];
    int s1 = vb ? csrc[e1] : csrc[beg];
    float p0 = va ? pexpf[e0 * 4 + head] : 0.f;
    float p1 = vb ? pexpf[e1 * 4 + head] : 0.f;
    float4 hv0 = *(const float4*)(h + (size_t)s0 * FDIM + c0);
    float4 hv1 = *(const float4*)(h + (size_t)s1 * FDIM + c0);
    const _Float16* h0 = (const _Float16*)&hv0;
    const _Float16* h1 = (const _Float16*)&hv1;
    de += p0 + p1;
#pragma unroll
    for (int j = 0; j < 8; ++j)
      acc[j] = fmaf(p1, (float)h1[j], fmaf(p0, (float)h0[j], acc[j]));
  }
#pragma unroll
  for (int j = 0; j < 8; ++j) acc[j] += __shfl_xor(acc[j], 32);
  de += __shfl_xor(de, 32);
  if (hw == 0) {
    float inv = 1.f / de;
    _Float16 o[8];
#pragma unroll
    for (int j = 0; j < 8; ++j) o[j] = (_Float16)gelu(acc[j] * inv + bias[c0 + j]);
    *(float4*)(out + (size_t)d * FDIM + c0) = *(const float4*)o;
  }
}

// ---------------- BN stats (XCD-swizzled, 8 units/graph)
template <int NPG>
__global__ void stats_k(const _Float16* __restrict__ x, float* __restrict__ sum,
                        float* __restrict__ sumsq) {
  SWIZ(8);
  constexpr int RPB = NPG / 8;
  int f = threadIdx.x;
  int r0 = g * NPG + u * RPB;
  float s = 0.f, sq = 0.f;
  for (int r = r0; r < r0 + RPB; ++r) {
    float gg = (float)x[(size_t)r * FDIM + f];
    s += gg;
    sq += gg * gg;
  }
  atomicAdd(&sum[f], s);
  atomicAdd(&sumsq[f], sq);
}

// ---------------- score (deferred BN affine fold; XCD-swizzled, NPG/4 units/graph)
template <int NPG, int NTOT>
__global__ void score_k(const _Float16* __restrict__ x, const float* __restrict__ bnsum,
                        const float* __restrict__ bnsq, const float* __restrict__ g_,
                        const float* __restrict__ be, const float* __restrict__ w,
                        float* __restrict__ score) {
  SWIZ(NPG / 4);
  constexpr float INV_N = 1.0f / NTOT;
  int tid = threadIdx.x, lane = tid & 63;
  int node = g * NPG + u * 4 + (tid >> 6);
  int c0 = lane * 4;
  float2 raw = *(const float2*)(x + (size_t)node * FDIM + c0);
  const _Float16* hh = (const _Float16*)&raw;
  float p = 0.f, shw = 0.f, nw = 0.f;
#pragma unroll
  for (int j = 0; j < 4; ++j) {
    int c = c0 + j;
    float mean = bnsum[c] * INV_N;
    float var = bnsq[c] * INV_N - mean * mean;
    float sc = g_[c] / sqrtf(var + BN_EPS);
    float sh = be[c] - mean * sc;
    float wv = w[c];
    p = fmaf((float)hh[j], sc * wv, p);
    shw = fmaf(sh, wv, shw);
    nw = fmaf(wv, wv, nw);
  }
#pragma unroll
  for (int off = 32; off > 0; off >>= 1) {
    p += __shfl_xor(p, off);
    shw += __shfl_xor(shw, off);
    nw += __shfl_xor(nw, off);
  }
  if (lane == 0) score[node] = (p + shw) / sqrtf(nw);
}

// ---------------- topk by rank selection (XCD-swizzled, TPG units/graph)
template <int NPG, int KEEP>
__global__ void topk_k(const float* __restrict__ score, float* __restrict__ vals,
                       int* __restrict__ gidx, int* __restrict__ inv) {
  constexpr int TPG = NPG / 256;
  SWIZ(TPG);
  __shared__ __align__(16) float sv[NPG];
  int tid = threadIdx.x;
  for (int i = tid; i < NPG; i += 256) sv[i] = score[g * NPG + i];
  __syncthreads();
  int cand = u * 256 + tid;
  float v = sv[cand];
  int rank = 0;
  const float4* sv4 = (const float4*)sv;
  for (int j4 = 0; j4 < NPG / 4; ++j4) {
    float4 qd = sv4[j4];
    int jb = j4 * 4;
    rank += (qd.x > v) || (qd.x == v && (jb + 0) < cand);
    rank += (qd.y > v) || (qd.y == v && (jb + 1) < cand);
    rank += (qd.z > v) || (qd.z == v && (jb + 2) < cand);
    rank += (qd.w > v) || (qd.w == v && (jb + 3) < cand);
  }
  if (rank < KEEP) {
    int r = g * KEEP + rank;
    vals[r] = v;
    int gg2 = g * NPG + cand;
    gidx[r] = gg2;
    if (inv) inv[gg2] = r;
  }
}

// ---------------- pool (BN+tanh fused gather + readout partials), L1 adds remap+deg2 ride
template <int NPG, int KEEP, bool EMIT, bool REMAP, int NTOT>
__global__ void pool_k(const _Float16* __restrict__ x, const int* __restrict__ gidx,
                       const float* __restrict__ vals, const float* __restrict__ bnsum,
                       const float* __restrict__ bnsq, const float* __restrict__ g_,
                       const float* __restrict__ be, _Float16* __restrict__ ah,
                       float* __restrict__ pmax, float* __restrict__ psum,
                       const int* __restrict__ src0, const int* __restrict__ dst0,
                       const int* __restrict__ inv, int* __restrict__ ns,
                       int* __restrict__ nd, int* __restrict__ deg2) {
  constexpr int PU = KEEP / 16;
  constexpr float INV_N = 1.0f / NTOT;
  int f = threadIdx.x;
  if ((int)blockIdx.x < 32 * PU) {
    SWIZ(PU);
    float mean = bnsum[f] * INV_N;
    float var = bnsq[f] * INV_N - mean * mean;
    float sc = g_[f] / sqrtf(var + BN_EPS);
    float sh = be[f] - mean * sc;
    float mx = -3.0e38f, sm = 0.f;
    int r0 = g * KEEP + u * 16;
#pragma unroll 4
    for (int j = 0; j < 16; ++j) {
      int r = r0 + j;
      float t = tanhf(vals[r]);
      float rawv = (float)x[(size_t)gidx[r] * FDIM + f];
      float vv = fmaf(rawv, sc, sh) * t;
      if (EMIT) ah[(size_t)r * FDIM + f] = (_Float16)vv;
      mx = fmaxf(mx, vv);
      sm += vv;
    }
    int blk = g * PU + u;
    pmax[(size_t)blk * FDIM + f] = mx;
    psum[(size_t)blk * FDIM + f] = sm;
  } else if (REMAP) {
    int bb = blockIdx.x - 32 * PU;
    int _x = bb & 7, _i = bb >> 3;
    int g = _x + 8 * (_i / 32), u = _i % 32;
    int e = g * 8192 + u * 256 + f;
    int aa = inv[src0[e]], b2 = inv[dst0[e]];
    bool ok = (aa >= 0) && (b2 >= 0);
    ns[e] = ok ? aa : -1;
    nd[e] = ok ? b2 : -1;
    if (ok) atomicAdd(&deg2[b2], 1);
  }
}

// ---------------- readout-final (both layers) + output linear
__global__ void final_k(const float* __restrict__ pmax1, const float* __restrict__ psum1,
                        const float* __restrict__ pmax2, const float* __restrict__ psum2,
                        const float* __restrict__ Wl, const float* __restrict__ bl,
                        float* __restrict__ out) {
  __shared__ float xs[2 * FDIM];
  int b = blockIdx.x, f = threadIdx.x;
  float mx1 = -3.0e38f, s1 = 0.f, mx2 = -3.0e38f, s2 = 0.f;
  for (int s = 0; s < KK1 / 16; ++s) {
    mx1 = fmaxf(mx1, pmax1[(size_t)(b * (KK1 / 16) + s) * FDIM + f]);
    s1 += psum1[(size_t)(b * (KK1 / 16) + s) * FDIM + f];
  }
  for (int s = 0; s < KK2 / 16; ++s) {
    mx2 = fmaxf(mx2, pmax2[(size_t)(b * (KK2 / 16) + s) * FDIM + f]);
    s2 += psum2[(size_t)(b * (KK2 / 16) + s) * FDIM + f];
  }
  xs[f] = mx1 + mx2;
  xs[FDIM + f] = s1 * (1.0f / KK1) + s2 * (1.0f / KK2);
  __syncthreads();
  float acc = bl[f];
  const float* wp = Wl + (size_t)f * 512;
  for (int j = 0; j < 512; ++j) acc = fmaf(xs[j], wp[j], acc);
  out[b * OUT_DIM + f] = acc;
}

extern "C" void kernel_launch(void* const* d_in, const int* in_sizes, int n_in,
                              void* d_out, int out_size, void* d_ws, size_t ws_size,
                              hipStream_t stream) {
  (void)in_sizes; (void)n_in; (void)out_size; (void)ws_size;
  const float* x   = (const float*)d_in[0];
  const int* eidx  = (const int*)d_in[1];
  const int* src   = eidx;
  const int* dst   = eidx + NE;
  const float* W1  = (const float*)d_in[3];
  const float* as1 = (const float*)d_in[4];
  const float* ad1 = (const float*)d_in[5];
  const float* b1  = (const float*)d_in[6];
  const float* g1  = (const float*)d_in[7];
  const float* be1 = (const float*)d_in[8];
  const float* pw1 = (const float*)d_in[9];
  const float* W2  = (const float*)d_in[10];
  const float* as2 = (const float*)d_in[11];
  const float* ad2 = (const float*)d_in[12];
  const float* b2  = (const float*)d_in[13];
  const float* g2  = (const float*)d_in[14];
  const float* be2 = (const float*)d_in[15];
  const float* pw2 = (const float*)d_in[16];
  const float* Wl  = (const float*)d_in[17];
  const float* bl  = (const float*)d_in[18];
  float* out = (float*)d_out;

  char* wsp = (char*)d_ws;
  size_t off = 0;
  auto alloc = [&](size_t bytes) -> void* {
    void* p = wsp + off;
    off += (bytes + 255) & ~(size_t)255;
    return p;
  };
  _Float16* h16 = (_Float16*)alloc((size_t)NN1 * FDIM * 2);
  _Float16* o16 = (_Float16*)alloc((size_t)NN1 * FDIM * 2);
  _Float16* ah  = (_Float16*)alloc((size_t)NN1 * IN_DIM * 2);
  _Float16* bt1 = (_Float16*)alloc((size_t)FDIM * IN_DIM * 2);
  _Float16* bt2 = (_Float16*)alloc((size_t)FDIM * FDIM * 2);
  float* asn    = (float*)alloc((size_t)NN1 * NHEADS * 4);
  float* adn    = (float*)alloc((size_t)NN1 * NHEADS * 4);
  float* pexp   = (float*)alloc((size_t)(NE + NN1) * 16);
  int*   deg1   = (int*)alloc((size_t)NN1 * 4);
  int*   deg2   = (int*)alloc((size_t)NN2 * 4);
  int*   rowst  = (int*)alloc((size_t)(NN1 + 1) * 4);
  int*   cursor = (int*)alloc((size_t)NN1 * 4);
  int*   csrc   = (int*)alloc((size_t)(NE + NN1) * 4);
  int*   ns     = (int*)alloc((size_t)NE * 4);
  int*   nd     = (int*)alloc((size_t)NE * 4);
  int*   inv1   = (int*)alloc((size_t)NN1 * 4);
  float* score  = (float*)alloc((size_t)NN1 * 4);
  float* vals   = (float*)alloc((size_t)NN2 * 4);
  int*   gidx   = (int*)alloc((size_t)NN2 * 4);
  float* bnst   = (float*)alloc(1024 * 4);
  float* pmax1  = (float*)alloc((size_t)(NN2 / 16) * FDIM * 4);
  float* psum1  = (float*)alloc((size_t)(NN2 / 16) * FDIM * 4);
  float* pmax2  = (float*)alloc((size_t)(NN3 / 16) * FDIM * 4);
  float* psum2  = (float*)alloc((size_t)(NN3 / 16) * FDIM * 4);

  // ---------- layer 1 ----------
  init_k<<<4608, 256, 0, stream>>>((const float4*)x, (half4v*)ah, W1, bt1, W2, bt2,
                                   deg1, deg2, inv1, bnst);
  gemm_attn_k<IN_DIM, 512, 1024, 0><<<dim3(2, 1024), 256, 0, stream>>>(
      ah, bt1, h16, as1, ad1, asn, adn, dst, deg1, nullptr, nullptr, nullptr);
  scanF_k<NN1><<<NN1 / 1024, 256, 0, stream>>>(deg1, rowst, cursor);
  csr_fill_k<1024, 32, 4><<<1024 + 128, 256, 0, stream>>>(
      src, dst, cursor, (const float4*)asn, (const float4*)adn, csrc, (float4*)pexp);
  gat_agg_k<1024><<<NN1 / 4, 256, 0, stream>>>(h16, rowst, csrc, pexp, b1, o16);
  stats_k<1024><<<256, 256, 0, stream>>>(o16, bnst, bnst + 256);
  score_k<1024, NN1><<<NN1 / 4, 256, 0, stream>>>(o16, bnst, bnst + 256, g1, be1, pw1, score);
  topk_k<1024, 512><<<NB * 4, 256, 0, stream>>>(score, vals, gidx, inv1);
  pool_k<1024, 512, true, true, NN1><<<1024 + 1024, 256, 0, stream>>>(
      o16, gidx, vals, bnst, bnst + 256, g1, be1, ah, pmax1, psum1,
      src, dst, inv1, ns, nd, deg2);
  // ---------- layer 2 ----------
  gemm_attn_k<FDIM, 256, 0, NN2><<<dim3(2, 256 + 8), 256, 0, stream>>>(
      ah, bt2, h16, as2, ad2, asn, adn, nullptr, nullptr, deg2, rowst, cursor);
  csr_fill_k<512, 32, 2><<<1024 + 64, 256, 0, stream>>>(
      ns, nd, cursor, (const float4*)asn, (const float4*)adn, csrc, (float4*)pexp);
  gat_agg_k<512><<<NN2 / 4, 256, 0, stream>>>(h16, rowst, csrc, pexp, b2, o16);
  stats_k<512><<<256, 256, 0, stream>>>(o16, bnst + 512, bnst + 768);
  score_k<512, NN2><<<NN2 / 4, 256, 0, stream>>>(o16, bnst + 512, bnst + 768, g2, be2, pw2,
                                                 score);
  topk_k<512, 256><<<NB * 2, 256, 0, stream>>>(score, vals, gidx, nullptr);
  pool_k<512, 256, false, false, NN2><<<512, 256, 0, stream>>>(
      o16, gidx, vals, bnst + 512, bnst + 768, g2, be2, nullptr, pmax2, psum2,
      nullptr, nullptr, nullptr, nullptr, nullptr, nullptr);
  // ---------- final ----------
  final_k<<<NB, 256, 0, stream>>>(pmax1, psum1, pmax2, psum2, Wl, bl, out);
}

// Round 12
// 320.388 us; speedup vs baseline: 1.4699x; 1.0887x over previous
//
#include <hip/hip_runtime.h>

#define NN1 32768
#define NE  262144
#define FDIM 256
#define NHEADS 4
#define IN_DIM 128
#define NB 32
#define KK1 512
#define NN2 16384   // NB*KK1
#define KK2 256
#define NN3 8192    // NB*KK2
#define OUT_DIM 256
#define BN_EPS 1e-5f
#define NEG_SLOPE 0.2f

typedef _Float16 half8 __attribute__((ext_vector_type(8)));
typedef float floatx4 __attribute__((ext_vector_type(4)));

__device__ __forceinline__ float lrelu(float x) { return x >= 0.f ? x : NEG_SLOPE * x; }
__device__ __forceinline__ float gelu(float v) {
  return 0.5f * v * (1.0f + erff(v * 0.7071067811865476f));
}
// XCD swizzle: total blocks = 32*U (U units/graph). blk%8 -> XCD; XCD x owns graphs {x,x+8,x+16,x+24}.
#define SWIZ(U) int g, u; { int _x = blockIdx.x & 7, _i = blockIdx.x >> 3; g = _x + 8 * (_i / (U)); u = _i % (U); }

// ---------- fused 2-level scan body of (deg+1): block b redundantly sums deg[0..b*1024)
template <int N>
__device__ void scan_body(const int* __restrict__ deg, int* __restrict__ rowst,
                          int* __restrict__ cursor, int b, int tid) {
  __shared__ int redS[4];
  __shared__ int swsumS[4];
  int lane = tid & 63, wv = tid >> 6;
  int part = 0;
  for (int idx = tid * 4; idx < b * 1024; idx += 1024) {
    int4 v = *(const int4*)&deg[idx];
    part += v.x + v.y + v.z + v.w;
  }
#pragma unroll
  for (int off = 32; off > 0; off >>= 1) part += __shfl_xor(part, off);
  if (lane == 0) redS[wv] = part;
  __syncthreads();
  int goff = redS[0] + redS[1] + redS[2] + redS[3] + b * 1024;  // + prior self loops
  int base = b * 1024 + tid * 4;
  int4 dv = *(const int4*)&deg[base];
  int v0 = dv.x + 1, v1 = dv.y + 1, v2 = dv.z + 1, v3 = dv.w + 1;
  int local = v0 + v1 + v2 + v3;
  int xx = local;
#pragma unroll
  for (int off = 1; off < 64; off <<= 1) {
    int t = __shfl_up(xx, off);
    if (lane >= off) xx += t;
  }
  if (lane == 63) swsumS[wv] = xx;
  __syncthreads();
  int woff = 0;
  for (int i = 0; i < wv; ++i) woff += swsumS[i];
  int ex = goff + woff + xx - local;
  int4 o;
  o.x = ex; o.y = ex + v0; o.z = ex + v0 + v1; o.w = ex + v0 + v1 + v2;
  *(int4*)&rowst[base] = o;
  *(int4*)&cursor[base] = o;
  if (b == (N / 1024) - 1 && tid == 0)
    rowst[N] = goff + swsumS[0] + swsumS[1] + swsumS[2] + swsumS[3];
}

template <int N>
__global__ void scanF_k(const int* __restrict__ deg, int* __restrict__ rowst,
                        int* __restrict__ cursor) {
  scan_body<N>(deg, rowst, cursor, blockIdx.x, threadIdx.x);
}

// ---------- init: W1^T, W2^T (fp16), zero deg1/deg2/inv1/bnstats (512 blocks)
__global__ void init_k(const float* __restrict__ W1, _Float16* __restrict__ bt1,
                       const float* __restrict__ W2, _Float16* __restrict__ bt2,
                       int* __restrict__ deg1, int* __restrict__ deg2,
                       int* __restrict__ inv1, float* __restrict__ bnst) {
  int blk = blockIdx.x, tid = threadIdx.x;
  if (blk < 128) {                        // W1[128][256] -> bt1[256][128]
    int idx = blk * 256 + tid;
    int n = idx >> 7, k = idx & 127;
    bt1[idx] = (_Float16)W1[k * FDIM + n];
  } else if (blk < 384) {                 // W2[256][256] -> bt2[256][256]
    int idx = (blk - 128) * 256 + tid;
    int n = idx >> 8, k = idx & 255;
    bt2[idx] = (_Float16)W2[k * FDIM + n];
  } else {
    int i = (blk - 384) * 256 + tid;
    deg1[i] = 0;
    inv1[i] = -1;
    if (i < NN2) deg2[i] = 0;
    if (i < 1024) bnst[i] = 0.f;
  }
}

// ---------------- MFMA fp16 GEMM + fused attn-coef epilogue + ride-along (deg OR scan)
// AT = float (convert in staging) or _Float16
template <typename AT, int K, int MBLK, int DEGU, int SCAN_N>
__global__ void gemm_attn_k(const AT* __restrict__ A, const _Float16* __restrict__ BT,
                            _Float16* __restrict__ C, const float* __restrict__ a_s,
                            const float* __restrict__ a_d, float* __restrict__ asn,
                            float* __restrict__ adn, const int* __restrict__ dstE,
                            int* __restrict__ deg, const int* __restrict__ sdeg,
                            int* __restrict__ srow, int* __restrict__ scur) {
  if ((int)blockIdx.y >= MBLK) {
    int unit = blockIdx.x + 2 * (blockIdx.y - MBLK);
    if constexpr (DEGU > 0) {
      int e = unit * 256 + threadIdx.x;
      if (e < NE) {
        int dd = dstE[e];
        if (dd >= 0) atomicAdd(&deg[dd], 1);
      }
    } else if constexpr (SCAN_N > 0) {
      scan_body<SCAN_N>(sdeg, srow, scur, unit, threadIdx.x);
    }
    return;
  }
  __shared__ _Float16 As[64 * 40];
  __shared__ _Float16 Bs[128 * 40];
  int tid = threadIdx.x;
  int lane = tid & 63, w = tid >> 6;
  int bm = blockIdx.y * 64, bn = blockIdx.x * 128;
  int wm = (w & 1) * 32, wn = (w >> 1) * 64;
  floatx4 acc[2][4] = {};
  int ar = tid >> 2, ac = (tid & 3) * 8;
  int br = tid >> 1, bc = (tid & 1) * 16;
  int fm = lane & 15, fq = (lane >> 4) * 8;
  for (int k0 = 0; k0 < K; k0 += 32) {
    __syncthreads();
    if constexpr (sizeof(AT) == 4) {      // fp32 A: load 2x float4, convert
      const float* Ap = (const float*)A + (size_t)(bm + ar) * K + k0 + ac;
      float4 a0 = *(const float4*)Ap;
      float4 a1 = *(const float4*)(Ap + 4);
      half8 hv;
      hv[0] = (_Float16)a0.x; hv[1] = (_Float16)a0.y;
      hv[2] = (_Float16)a0.z; hv[3] = (_Float16)a0.w;
      hv[4] = (_Float16)a1.x; hv[5] = (_Float16)a1.y;
      hv[6] = (_Float16)a1.z; hv[7] = (_Float16)a1.w;
      *(half8*)&As[ar * 40 + ac] = hv;
    } else {
      *(half8*)&As[ar * 40 + ac] = *(const half8*)((const _Float16*)A + (size_t)(bm + ar) * K + k0 + ac);
    }
    *(half8*)&Bs[br * 40 + bc] = *(const half8*)&BT[(size_t)(bn + br) * K + k0 + bc];
    *(half8*)&Bs[br * 40 + bc + 8] = *(const half8*)&BT[(size_t)(bn + br) * K + k0 + bc + 8];
    __syncthreads();
    half8 af[2], bf[4];
#pragma unroll
    for (int mt = 0; mt < 2; ++mt)
      af[mt] = *(const half8*)&As[(wm + mt * 16 + fm) * 40 + fq];
#pragma unroll
    for (int nt = 0; nt < 4; ++nt)
      bf[nt] = *(const half8*)&Bs[(wn + nt * 16 + fm) * 40 + fq];
#pragma unroll
    for (int mt = 0; mt < 2; ++mt)
#pragma unroll
      for (int nt = 0; nt < 4; ++nt)
        acc[mt][nt] = __builtin_amdgcn_mfma_f32_16x16x32_f16(af[mt], bf[nt], acc[mt][nt], 0, 0, 0);
  }
  int row0 = bm + wm + (lane >> 4) * 4;
  int col0 = bn + wn + (lane & 15);
#pragma unroll
  for (int mt = 0; mt < 2; ++mt)
#pragma unroll
    for (int nt = 0; nt < 4; ++nt) {
      _Float16* cp = C + (size_t)(row0 + mt * 16) * FDIM + col0 + nt * 16;
#pragma unroll
      for (int i = 0; i < 4; ++i) cp[(size_t)i * FDIM] = (_Float16)acc[mt][nt][i];
    }
  // attn-coef epilogue (wave = one head)
  int head = (bn + wn) >> 6;
  float ps[2][4] = {}, pd[2][4] = {};
#pragma unroll
  for (int nt = 0; nt < 4; ++nt) {
    int c = bn + wn + (lane & 15) + nt * 16;
    float asv = a_s[c], adv = a_d[c];
#pragma unroll
    for (int mt = 0; mt < 2; ++mt)
#pragma unroll
      for (int i = 0; i < 4; ++i) {
        ps[mt][i] = fmaf(acc[mt][nt][i], asv, ps[mt][i]);
        pd[mt][i] = fmaf(acc[mt][nt][i], adv, pd[mt][i]);
      }
  }
#pragma unroll
  for (int off = 8; off >= 1; off >>= 1)
#pragma unroll
    for (int mt = 0; mt < 2; ++mt)
#pragma unroll
      for (int i = 0; i < 4; ++i) {
        ps[mt][i] += __shfl_xor(ps[mt][i], off);
        pd[mt][i] += __shfl_xor(pd[mt][i], off);
      }
  if ((lane & 15) == 0) {
#pragma unroll
    for (int mt = 0; mt < 2; ++mt)
#pragma unroll
      for (int i = 0; i < 4; ++i) {
        int r = row0 + mt * 16 + i;
        asn[r * 4 + head] = ps[mt][i];
        adn[r * 4 + head] = pd[mt][i];
      }
  }
}

// ---------------- CSR fill (XCD-swizzled): EU edge-units + SU selfloop-units per graph
template <int NPG, int EU, int SU>
__global__ void csr_fill_k(const int* __restrict__ src, const int* __restrict__ dst,
                           int* __restrict__ cursor, const float4* __restrict__ asn4,
                           const float4* __restrict__ adn4, int* __restrict__ csrc,
                           float4* __restrict__ pexp) {
  int tid = threadIdx.x;
  int s, d;
  if ((int)blockIdx.x < 32 * EU) {
    SWIZ(EU);
    int e = g * 8192 + u * 256 + tid;
    d = dst[e];
    if (d < 0) return;
    s = src[e];
  } else {
    int bb = blockIdx.x - 32 * EU;
    int _x = bb & 7, _i = bb >> 3;
    int g = _x + 8 * (_i / SU), u = _i % SU;
    s = d = g * NPG + u * 256 + tid;
  }
  int pos = atomicAdd(&cursor[d], 1);
  csrc[pos] = s;
  float4 A4 = asn4[s], B4 = adn4[d];
  float4 p;
  p.x = expf(lrelu(A4.x + B4.x));
  p.y = expf(lrelu(A4.y + B4.y));
  p.z = expf(lrelu(A4.z + B4.z));
  p.w = expf(lrelu(A4.w + B4.w));
  pexp[pos] = p;
}

// ---------------- GAT aggregate + GELU -> o16 (XCD-swizzled; 8-edge ILP, 4 per half-wave)
template <int NPG>
__global__ void gat_agg_k(const _Float16* __restrict__ h, const int* __restrict__ rowstart,
                          const int* __restrict__ csrc, const float* __restrict__ pexpf,
                          const float* __restrict__ bias, _Float16* __restrict__ out) {
  SWIZ(NPG / 4);
  int tid = threadIdx.x, lane = tid & 63;
  int hw = lane >> 5, l = lane & 31;
  int d = g * NPG + u * 4 + (tid >> 6);
  int beg = rowstart[d], end = rowstart[d + 1];
  int c0 = l * 8, head = l >> 3;
  float acc[8] = {};
  float de = 0.f;
  for (int i = beg; i < end; i += 8) {
    int e[4];
    float p[4];
    float4 hv[4];
#pragma unroll
    for (int j = 0; j < 4; ++j) {
      e[j] = i + hw + 2 * j;
      bool va = e[j] < end;
      int s = va ? csrc[e[j]] : csrc[beg];
      p[j] = va ? pexpf[e[j] * 4 + head] : 0.f;
      hv[j] = *(const float4*)(h + (size_t)s * FDIM + c0);
    }
#pragma unroll
    for (int j = 0; j < 4; ++j) {
      const _Float16* hh = (const _Float16*)&hv[j];
      de += p[j];
#pragma unroll
      for (int q = 0; q < 8; ++q) acc[q] = fmaf(p[j], (float)hh[q], acc[q]);
    }
  }
#pragma unroll
  for (int j = 0; j < 8; ++j) acc[j] += __shfl_xor(acc[j], 32);
  de += __shfl_xor(de, 32);
  if (hw == 0) {
    float inv = 1.f / de;
    _Float16 o[8];
#pragma unroll
    for (int j = 0; j < 8; ++j) o[j] = (_Float16)gelu(acc[j] * inv + bias[c0 + j]);
    *(float4*)(out + (size_t)d * FDIM + c0) = *(const float4*)o;
  }
}

// ---------------- BN stats (XCD-swizzled, 8 units/graph)
template <int NPG>
__global__ void stats_k(const _Float16* __restrict__ x, float* __restrict__ sum,
                        float* __restrict__ sumsq) {
  SWIZ(8);
  constexpr int RPB = NPG / 8;
  int f = threadIdx.x;
  int r0 = g * NPG + u * RPB;
  float s = 0.f, sq = 0.f;
  for (int r = r0; r < r0 + RPB; ++r) {
    float gg = (float)x[(size_t)r * FDIM + f];
    s += gg;
    sq += gg * gg;
  }
  atomicAdd(&sum[f], s);
  atomicAdd(&sumsq[f], sq);
}

// ---------------- score (deferred BN affine fold; XCD-swizzled, NPG/4 units/graph)
template <int NPG, int NTOT>
__global__ void score_k(const _Float16* __restrict__ x, const float* __restrict__ bnsum,
                        const float* __restrict__ bnsq, const float* __restrict__ g_,
                        const float* __restrict__ be, const float* __restrict__ w,
                        float* __restrict__ score) {
  SWIZ(NPG / 4);
  constexpr float INV_N = 1.0f / NTOT;
  int tid = threadIdx.x, lane = tid & 63;
  int node = g * NPG + u * 4 + (tid >> 6);
  int c0 = lane * 4;
  float2 raw = *(const float2*)(x + (size_t)node * FDIM + c0);
  const _Float16* hh = (const _Float16*)&raw;
  float p = 0.f, shw = 0.f, nw = 0.f;
#pragma unroll
  for (int j = 0; j < 4; ++j) {
    int c = c0 + j;
    float mean = bnsum[c] * INV_N;
    float var = bnsq[c] * INV_N - mean * mean;
    float sc = g_[c] / sqrtf(var + BN_EPS);
    float sh = be[c] - mean * sc;
    float wv = w[c];
    p = fmaf((float)hh[j], sc * wv, p);
    shw = fmaf(sh, wv, shw);
    nw = fmaf(wv, wv, nw);
  }
#pragma unroll
  for (int off = 32; off > 0; off >>= 1) {
    p += __shfl_xor(p, off);
    shw += __shfl_xor(shw, off);
    nw += __shfl_xor(nw, off);
  }
  if (lane == 0) score[node] = (p + shw) / sqrtf(nw);
}

// ---------------- topk by split-rank selection: 64 candidates/block, rank loop split 4-way
template <int NPG, int KEEP>
__global__ void topk_k(const float* __restrict__ score, float* __restrict__ vals,
                       int* __restrict__ gidx, int* __restrict__ inv) {
  constexpr int UPG = NPG / 64;   // units (blocks) per graph
  SWIZ(UPG);
  __shared__ __align__(16) float sv[NPG];
  __shared__ int prt[256];
  int tid = threadIdx.x;
  float4* svw = (float4*)sv;
  const float4* srcp = (const float4*)(score + g * NPG);
  for (int i = tid; i < NPG / 4; i += 256) svw[i] = srcp[i];
  __syncthreads();
  int cl = tid & 63, sp = tid >> 6;
  int cand = u * 64 + cl;
  float v = sv[cand];
  int rank = 0;
  const float4* sv4 = (const float4*)sv;
  int j0 = sp * (NPG / 16), j1 = j0 + NPG / 16;
  for (int j4 = j0; j4 < j1; ++j4) {
    float4 qd = sv4[j4];
    int jb = j4 * 4;
    rank += (qd.x > v) || (qd.x == v && (jb + 0) < cand);
    rank += (qd.y > v) || (qd.y == v && (jb + 1) < cand);
    rank += (qd.z > v) || (qd.z == v && (jb + 2) < cand);
    rank += (qd.w > v) || (qd.w == v && (jb + 3) < cand);
  }
  prt[tid] = rank;
  __syncthreads();
  if (tid < 64) {
    int r = prt[tid] + prt[tid + 64] + prt[tid + 128] + prt[tid + 192];
    if (r < KEEP) {
      int cand2 = u * 64 + tid;
      int rr = g * KEEP + r;
      vals[rr] = sv[cand2];
      int gg2 = g * NPG + cand2;
      gidx[rr] = gg2;
      if (inv) inv[gg2] = rr;
    }
  }
}

// ---------------- pool (BN+tanh fused gather + readout partials), L1 adds remap+deg2 ride
template <int NPG, int KEEP, bool EMIT, bool REMAP, int NTOT>
__global__ void pool_k(const _Float16* __restrict__ x, const int* __restrict__ gidx,
                       const float* __restrict__ vals, const float* __restrict__ bnsum,
                       const float* __restrict__ bnsq, const float* __restrict__ g_,
                       const float* __restrict__ be, _Float16* __restrict__ ah,
                       float* __restrict__ pmax, float* __restrict__ psum,
                       const int* __restrict__ src0, const int* __restrict__ dst0,
                       const int* __restrict__ inv, int* __restrict__ ns,
                       int* __restrict__ nd, int* __restrict__ deg2) {
  constexpr int PU = KEEP / 16;
  constexpr float INV_N = 1.0f / NTOT;
  int f = threadIdx.x;
  if ((int)blockIdx.x < 32 * PU) {
    SWIZ(PU);
    float mean = bnsum[f] * INV_N;
    float var = bnsq[f] * INV_N - mean * mean;
    float sc = g_[f] / sqrtf(var + BN_EPS);
    float sh = be[f] - mean * sc;
    float mx = -3.0e38f, sm = 0.f;
    int r0 = g * KEEP + u * 16;
#pragma unroll 4
    for (int j = 0; j < 16; ++j) {
      int r = r0 + j;
      float t = tanhf(vals[r]);
      float rawv = (float)x[(size_t)gidx[r] * FDIM + f];
      float vv = fmaf(rawv, sc, sh) * t;
      if (EMIT) ah[(size_t)r * FDIM + f] = (_Float16)vv;
      mx = fmaxf(mx, vv);
      sm += vv;
    }
    int blk = g * PU + u;
    pmax[(size_t)blk * FDIM + f] = mx;
    psum[(size_t)blk * FDIM + f] = sm;
  } else if (REMAP) {
    int bb = blockIdx.x - 32 * PU;
    int _x = bb & 7, _i = bb >> 3;
    int g = _x + 8 * (_i / 32), u = _i % 32;
    int e = g * 8192 + u * 256 + f;
    int aa = inv[src0[e]], b2 = inv[dst0[e]];
    bool ok = (aa >= 0) && (b2 >= 0);
    ns[e] = ok ? aa : -1;
    nd[e] = ok ? b2 : -1;
    if (ok) atomicAdd(&deg2[b2], 1);
  }
}

// ---------------- readout-final (both layers) + output linear
__global__ void final_k(const float* __restrict__ pmax1, const float* __restrict__ psum1,
                        const float* __restrict__ pmax2, const float* __restrict__ psum2,
                        const float* __restrict__ Wl, const float* __restrict__ bl,
                        float* __restrict__ out) {
  __shared__ float xs[2 * FDIM];
  int b = blockIdx.x, f = threadIdx.x;
  float mx1 = -3.0e38f, s1 = 0.f, mx2 = -3.0e38f, s2 = 0.f;
  for (int s = 0; s < KK1 / 16; ++s) {
    mx1 = fmaxf(mx1, pmax1[(size_t)(b * (KK1 / 16) + s) * FDIM + f]);
    s1 += psum1[(size_t)(b * (KK1 / 16) + s) * FDIM + f];
  }
  for (int s = 0; s < KK2 / 16; ++s) {
    mx2 = fmaxf(mx2, pmax2[(size_t)(b * (KK2 / 16) + s) * FDIM + f]);
    s2 += psum2[(size_t)(b * (KK2 / 16) + s) * FDIM + f];
  }
  xs[f] = mx1 + mx2;
  xs[FDIM + f] = s1 * (1.0f / KK1) + s2 * (1.0f / KK2);
  __syncthreads();
  float acc = bl[f];
  const float* wp = Wl + (size_t)f * 512;
  for (int j = 0; j < 512; ++j) acc = fmaf(xs[j], wp[j], acc);
  out[b * OUT_DIM + f] = acc;
}

extern "C" void kernel_launch(void* const* d_in, const int* in_sizes, int n_in,
                              void* d_out, int out_size, void* d_ws, size_t ws_size,
                              hipStream_t stream) {
  (void)in_sizes; (void)n_in; (void)out_size; (void)ws_size;
  const float* x   = (const float*)d_in[0];
  const int* eidx  = (const int*)d_in[1];
  const int* src   = eidx;
  const int* dst   = eidx + NE;
  const float* W1  = (const float*)d_in[3];
  const float* as1 = (const float*)d_in[4];
  const float* ad1 = (const float*)d_in[5];
  const float* b1  = (const float*)d_in[6];
  const float* g1  = (const float*)d_in[7];
  const float* be1 = (const float*)d_in[8];
  const float* pw1 = (const float*)d_in[9];
  const float* W2  = (const float*)d_in[10];
  const float* as2 = (const float*)d_in[11];
  const float* ad2 = (const float*)d_in[12];
  const float* b2  = (const float*)d_in[13];
  const float* g2  = (const float*)d_in[14];
  const float* be2 = (const float*)d_in[15];
  const float* pw2 = (const float*)d_in[16];
  const float* Wl  = (const float*)d_in[17];
  const float* bl  = (const float*)d_in[18];
  float* out = (float*)d_out;

  char* wsp = (char*)d_ws;
  size_t off = 0;
  auto alloc = [&](size_t bytes) -> void* {
    void* p = wsp + off;
    off += (bytes + 255) & ~(size_t)255;
    return p;
  };
  _Float16* h16 = (_Float16*)alloc((size_t)NN1 * FDIM * 2);
  _Float16* o16 = (_Float16*)alloc((size_t)NN1 * FDIM * 2);
  _Float16* ah  = (_Float16*)alloc((size_t)NN2 * FDIM * 2);   // layer-2 GEMM A
  _Float16* bt1 = (_Float16*)alloc((size_t)FDIM * IN_DIM * 2);
  _Float16* bt2 = (_Float16*)alloc((size_t)FDIM * FDIM * 2);
  float* asn    = (float*)alloc((size_t)NN1 * NHEADS * 4);
  float* adn    = (float*)alloc((size_t)NN1 * NHEADS * 4);
  float* pexp   = (float*)alloc((size_t)(NE + NN1) * 16);
  int*   deg1   = (int*)alloc((size_t)NN1 * 4);
  int*   deg2   = (int*)alloc((size_t)NN2 * 4);
  int*   rowst  = (int*)alloc((size_t)(NN1 + 1) * 4);
  int*   cursor = (int*)alloc((size_t)NN1 * 4);
  int*   csrc   = (int*)alloc((size_t)(NE + NN1) * 4);
  int*   ns     = (int*)alloc((size_t)NE * 4);
  int*   nd     = (int*)alloc((size_t)NE * 4);
  int*   inv1   = (int*)alloc((size_t)NN1 * 4);
  float* score  = (float*)alloc((size_t)NN1 * 4);
  float* vals   = (float*)alloc((size_t)NN2 * 4);
  int*   gidx   = (int*)alloc((size_t)NN2 * 4);
  float* bnst   = (float*)alloc(1024 * 4);
  float* pmax1  = (float*)alloc((size_t)(NN2 / 16) * FDIM * 4);
  float* psum1  = (float*)alloc((size_t)(NN2 / 16) * FDIM * 4);
  float* pmax2  = (float*)alloc((size_t)(NN3 / 16) * FDIM * 4);
  float* psum2  = (float*)alloc((size_t)(NN3 / 16) * FDIM * 4);

  // ---------- layer 1 ----------
  init_k<<<512, 256, 0, stream>>>(W1, bt1, W2, bt2, deg1, deg2, inv1, bnst);
  gemm_attn_k<float, IN_DIM, 512, 1024, 0><<<dim3(2, 1024), 256, 0, stream>>>(
      x, bt1, h16, as1, ad1, asn, adn, dst, deg1, nullptr, nullptr, nullptr);
  scanF_k<NN1><<<NN1 / 1024, 256, 0, stream>>>(deg1, rowst, cursor);
  csr_fill_k<1024, 32, 4><<<1024 + 128, 256, 0, stream>>>(
      src, dst, cursor, (const float4*)asn, (const float4*)adn, csrc, (float4*)pexp);
  gat_agg_k<1024><<<NN1 / 4, 256, 0, stream>>>(h16, rowst, csrc, pexp, b1, o16);
  stats_k<1024><<<256, 256, 0, stream>>>(o16, bnst, bnst + 256);
  score_k<1024, NN1><<<NN1 / 4, 256, 0, stream>>>(o16, bnst, bnst + 256, g1, be1, pw1, score);
  topk_k<1024, 512><<<NB * 16, 256, 0, stream>>>(score, vals, gidx, inv1);
  pool_k<1024, 512, true, true, NN1><<<1024 + 1024, 256, 0, stream>>>(
      o16, gidx, vals, bnst, bnst + 256, g1, be1, ah, pmax1, psum1,
      src, dst, inv1, ns, nd, deg2);
  // ---------- layer 2 ----------
  gemm_attn_k<_Float16, FDIM, 256, 0, NN2><<<dim3(2, 256 + 8), 256, 0, stream>>>(
      ah, bt2, h16, as2, ad2, asn, adn, nullptr, nullptr, deg2, rowst, cursor);
  csr_fill_k<512, 32, 2><<<1024 + 64, 256, 0, stream>>>(
      ns, nd, cursor, (const float4*)asn, (const float4*)adn, csrc, (float4*)pexp);
  gat_agg_k<512><<<NN2 / 4, 256, 0, stream>>>(h16, rowst, csrc, pexp, b2, o16);
  stats_k<512><<<256, 256, 0, stream>>>(o16, bnst + 512, bnst + 768);
  score_k<512, NN2><<<NN2 / 4, 256, 0, stream>>>(o16, bnst + 512, bnst + 768, g2, be2, pw2,
                                                 score);
  topk_k<512, 256><<<NB * 8, 256, 0, stream>>>(score, vals, gidx, nullptr);
  pool_k<512, 256, false, false, NN2><<<512, 256, 0, stream>>>(
      o16, gidx, vals, bnst + 512, bnst + 768, g2, be2, nullptr, pmax2, psum2,
      nullptr, nullptr, nullptr, nullptr, nullptr, nullptr);
  // ---------- final ----------
  final_k<<<NB, 256, 0, stream>>>(pmax1, psum1, pmax2, psum2, Wl, bl, out);
}